// Round 12
// baseline (350.848 us; speedup 1.0000x reference)
//
#include <hip/hip_runtime.h>

#define DF 128
#define SCAN_TILE 2048   // elements per scan block (256 thr x 8)

typedef __attribute__((ext_vector_type(8))) short bf16x8;
typedef __attribute__((ext_vector_type(4))) float f32x4;

__device__ __forceinline__ ushort f2b(float f) {      // f32 -> bf16 RNE
    uint u = __float_as_uint(f);
    u += 0x7FFF + ((u >> 16) & 1);
    return (ushort)(u >> 16);
}
__device__ __forceinline__ float blo(uint v) { return __uint_as_float(v << 16); }
__device__ __forceinline__ float bhi(uint v) { return __uint_as_float(v & 0xFFFF0000u); }
__device__ __forceinline__ uint pk(float lo, float hi) {
    return (uint)f2b(lo) | ((uint)f2b(hi) << 16);
}

// ---------- CSR build ----------

__global__ void count_kernel(const int* __restrict__ dst, int* __restrict__ cnt, int E) {
    int e = blockIdx.x * blockDim.x + threadIdx.x;
    if (e < E) atomicAdd(&cnt[dst[e]], 1);
}

// pass 1: per-block sums of 2048-element tiles
__global__ __launch_bounds__(256) void scan_reduce(const int* __restrict__ cnt,
                                                   int* __restrict__ bsum, int N) {
    __shared__ int sw[4];
    const int tid = threadIdx.x, lane = tid & 63, wid = tid >> 6;
    const int base = blockIdx.x * SCAN_TILE + tid * 8;
    int s = 0;
    #pragma unroll
    for (int j = 0; j < 8; ++j) { int i = base + j; if (i < N) s += cnt[i]; }
    #pragma unroll
    for (int off = 1; off < 64; off <<= 1) s += __shfl_xor(s, off);
    if (lane == 0) sw[wid] = s;
    __syncthreads();
    if (tid == 0) bsum[blockIdx.x] = sw[0] + sw[1] + sw[2] + sw[3];
}

// pass 2: one wave scans the (<=64) block sums in place; writes total to row_start[N]
__global__ __launch_bounds__(64) void scan_blocksums(int* __restrict__ bsum, int nb,
                                                     int* __restrict__ row_start, int N) {
    const int lane = threadIdx.x;
    int v = (lane < nb) ? bsum[lane] : 0;
    int incl = v;
    #pragma unroll
    for (int off = 1; off < 64; off <<= 1) {
        int t = __shfl_up(incl, off);
        if (lane >= off) incl += t;
    }
    if (lane < nb) bsum[lane] = incl - v;          // exclusive
    if (lane == 63) row_start[N] = incl;           // grand total
}

// pass 3: full exclusive scan + emit row_start/cur/inv
__global__ __launch_bounds__(256) void scan_apply(const int* __restrict__ cnt,
                                                  const int* __restrict__ bsum,
                                                  int* __restrict__ row_start,
                                                  int* __restrict__ cur,
                                                  float* __restrict__ inv, int N) {
    __shared__ int sw[4];
    const int tid = threadIdx.x, lane = tid & 63, wid = tid >> 6;
    const int base = blockIdx.x * SCAN_TILE + tid * 8;
    int v[8];
    int tsum = 0;
    #pragma unroll
    for (int j = 0; j < 8; ++j) {
        int i = base + j;
        v[j] = (i < N) ? cnt[i] : 0;
        tsum += v[j];
    }
    // exclusive scan of per-thread sums across the block
    int incl = tsum;
    #pragma unroll
    for (int off = 1; off < 64; off <<= 1) {
        int t = __shfl_up(incl, off);
        if (lane >= off) incl += t;
    }
    if (lane == 63) sw[wid] = incl;
    __syncthreads();
    int woff = 0;
    #pragma unroll
    for (int k = 0; k < 4; ++k) woff += (k < wid) ? sw[k] : 0;
    int run = bsum[blockIdx.x] + woff + (incl - tsum);
    #pragma unroll
    for (int j = 0; j < 8; ++j) {
        int i = base + j;
        if (i < N) {
            row_start[i] = run;
            cur[i]       = run;
            inv[i]       = 1.0f / fmaxf((float)v[j], 1.0f);
        }
        run += v[j];
    }
}

__global__ void place_kernel(const int* __restrict__ src, const int* __restrict__ dst,
                             int* __restrict__ cur, ushort* __restrict__ col, int E) {
    int e = blockIdx.x * blockDim.x + threadIdx.x;
    if (e < E) {
        int p = atomicAdd(&cur[dst[e]], 1);
        col[p] = (ushort)src[e];          // N=50000 < 65536
    }
}

// ---------- conversions ----------

__global__ void cvt_x_kernel(const float* __restrict__ in, ushort* __restrict__ out, int n4) {
    int i = blockIdx.x * blockDim.x + threadIdx.x;   // index of float4
    if (i < n4) {
        float4 v = *reinterpret_cast<const float4*>(in + (long long)i * 4);
        uint2 p;
        p.x = pk(v.x, v.y);
        p.y = pk(v.z, v.w);
        *reinterpret_cast<uint2*>(out + (long long)i * 4) = p;
    }
}

struct WPtrs { const float* p[9]; };

__global__ void cvt_w_kernel(WPtrs w, ushort* __restrict__ out) {
    int m = blockIdx.y;
    int i = blockIdx.x * 256 + threadIdx.x;          // 0..16383
    out[m * 16384 + i] = f2b(w.p[m][i]);
}

// ---------- aggregate: bf16 gather-mean, wave per node ----------
// Half-wave scheme: 32 lanes x uint2 (8B) cover one 256B row; the two halves
// process different neighbor rows -> 8 row-gathers in flight per wave, no
// shfl in the load chain. Final __shfl_xor(32) combine; half 0 writes.

__global__ __launch_bounds__(256) void aggregate_kernel(
        const ushort* __restrict__ H,
        const int* __restrict__ row_start, const ushort* __restrict__ col,
        const float* __restrict__ inv, ushort* __restrict__ M, int N) {
    const int node = blockIdx.x * 4 + (threadIdx.x >> 6);
    const int lane = threadIdx.x & 63;
    if (node >= N) return;
    const int s = row_start[node], e = row_start[node + 1];
    const int half = lane >> 5, l32 = lane & 31;
    const uint2* __restrict__ Hu = reinterpret_cast<const uint2*>(H);
    float a0 = 0.f, a1 = 0.f, a2 = 0.f, a3 = 0.f;
    int j = s;
    for (; j + 8 <= e; j += 8) {
        int n0 = (int)col[j + 0 + half];
        int n1 = (int)col[j + 2 + half];
        int n2 = (int)col[j + 4 + half];
        int n3 = (int)col[j + 6 + half];
        uint2 v0 = Hu[n0 * 32 + l32];
        uint2 v1 = Hu[n1 * 32 + l32];
        uint2 v2 = Hu[n2 * 32 + l32];
        uint2 v3 = Hu[n3 * 32 + l32];
        a0 += blo(v0.x); a1 += bhi(v0.x); a2 += blo(v0.y); a3 += bhi(v0.y);
        a0 += blo(v1.x); a1 += bhi(v1.x); a2 += blo(v1.y); a3 += bhi(v1.y);
        a0 += blo(v2.x); a1 += bhi(v2.x); a2 += blo(v2.y); a3 += bhi(v2.y);
        a0 += blo(v3.x); a1 += bhi(v3.x); a2 += blo(v3.y); a3 += bhi(v3.y);
    }
    for (; j + 2 <= e; j += 2) {
        int n0 = (int)col[j + half];
        uint2 v0 = Hu[n0 * 32 + l32];
        a0 += blo(v0.x); a1 += bhi(v0.x); a2 += blo(v0.y); a3 += bhi(v0.y);
    }
    if (j < e && half == 0) {
        int n0 = (int)col[j];
        uint2 v0 = Hu[n0 * 32 + l32];
        a0 += blo(v0.x); a1 += bhi(v0.x); a2 += blo(v0.y); a3 += bhi(v0.y);
    }
    a0 += __shfl_xor(a0, 32);
    a1 += __shfl_xor(a1, 32);
    a2 += __shfl_xor(a2, 32);
    a3 += __shfl_xor(a3, 32);
    if (half == 0) {
        const float iv = inv[node];
        uint2 p;
        p.x = pk(a0 * iv, a1 * iv);
        p.y = pk(a2 * iv, a3 * iv);
        reinterpret_cast<uint2*>(M + (long long)node * DF)[l32] = p;
    }
}

// ---------- dual-GEMM via MFMA: outB = relu( A1@W1.T + A2@W2.T + b ) ----------
// block = 64 rows x 128 cols, 4 waves; wave w owns cols [w*32, w*32+32).
// In-place safe: block writes only its own rows, after all its reads.

__global__ __launch_bounds__(256) void gemm_mfma(
    const ushort* __restrict__ A1,
    const ushort* __restrict__ A2,
    const ushort* __restrict__ W1,
    const ushort* __restrict__ W2,
    const float* __restrict__ bias,
    ushort* __restrict__ outB,
    int n)
{
    const int lane = threadIdx.x & 63;
    const int w    = threadIdx.x >> 6;
    const int n0   = blockIdx.x * 64;
    const int r16  = lane & 15;
    const int kq   = (lane >> 4) * 8;

    f32x4 acc[4][2];
    #pragma unroll
    for (int i = 0; i < 4; ++i)
        #pragma unroll
        for (int j = 0; j < 2; ++j) acc[i][j] = (f32x4){0.f, 0.f, 0.f, 0.f};

    #pragma unroll
    for (int pass = 0; pass < 2; ++pass) {
        const ushort* A = pass ? A2 : A1;
        const ushort* W = pass ? W2 : W1;
        #pragma unroll
        for (int kk = 0; kk < 4; ++kk) {
            const int k0 = kk * 32 + kq;
            bf16x8 b[2];
            #pragma unroll
            for (int ct = 0; ct < 2; ++ct) {
                int o = w * 32 + ct * 16 + r16;
                b[ct] = *reinterpret_cast<const bf16x8*>(W + o * DF + k0);
            }
            #pragma unroll
            for (int rt = 0; rt < 4; ++rt) {
                int row = n0 + rt * 16 + r16;
                if (row >= n) row = n - 1;
                bf16x8 a = *reinterpret_cast<const bf16x8*>(A + (long long)row * DF + k0);
                #pragma unroll
                for (int ct = 0; ct < 2; ++ct)
                    acc[rt][ct] = __builtin_amdgcn_mfma_f32_16x16x32_bf16(a, b[ct], acc[rt][ct], 0, 0, 0);
            }
        }
    }

    // C/D layout: col = lane&15, row = (lane>>4)*4 + reg
    #pragma unroll
    for (int rt = 0; rt < 4; ++rt) {
        #pragma unroll
        for (int ct = 0; ct < 2; ++ct) {
            const int c = w * 32 + ct * 16 + r16;
            const float bv = bias[c];
            #pragma unroll
            for (int r = 0; r < 4; ++r) {
                int row = n0 + rt * 16 + (lane >> 4) * 4 + r;
                if (row < n) {
                    float v = fmaxf(acc[rt][ct][r] + bv, 0.0f);
                    outB[(long long)row * DF + c] = f2b(v);
                }
            }
        }
    }
}

// ---------- fused L4 + FC: h4 = relu(M@W1.T + H@W2.T + b4) -> LDS; out = h4@Wf.T + bf ----------
#define SHP 136   // ushort stride: 272B rows (16B aligned), 2-way LDS bank alias (free)

__global__ __launch_bounds__(256) void gemm_mfma_fc(
    const ushort* __restrict__ A1,
    const ushort* __restrict__ A2,
    const ushort* __restrict__ W1,
    const ushort* __restrict__ W2,
    const float* __restrict__ bias1,
    const ushort* __restrict__ Wf,
    const float* __restrict__ biasf,
    float* __restrict__ out,
    int n)
{
    __shared__ ushort sH[64 * SHP];

    const int lane = threadIdx.x & 63;
    const int w    = threadIdx.x >> 6;
    const int n0   = blockIdx.x * 64;
    const int r16  = lane & 15;
    const int kq   = (lane >> 4) * 8;

    f32x4 acc[4][2];
    #pragma unroll
    for (int i = 0; i < 4; ++i)
        #pragma unroll
        for (int j = 0; j < 2; ++j) acc[i][j] = (f32x4){0.f, 0.f, 0.f, 0.f};

    #pragma unroll
    for (int pass = 0; pass < 2; ++pass) {
        const ushort* A = pass ? A2 : A1;
        const ushort* W = pass ? W2 : W1;
        #pragma unroll
        for (int kk = 0; kk < 4; ++kk) {
            const int k0 = kk * 32 + kq;
            bf16x8 b[2];
            #pragma unroll
            for (int ct = 0; ct < 2; ++ct) {
                int o = w * 32 + ct * 16 + r16;
                b[ct] = *reinterpret_cast<const bf16x8*>(W + o * DF + k0);
            }
            #pragma unroll
            for (int rt = 0; rt < 4; ++rt) {
                int row = n0 + rt * 16 + r16;
                if (row >= n) row = n - 1;
                bf16x8 a = *reinterpret_cast<const bf16x8*>(A + (long long)row * DF + k0);
                #pragma unroll
                for (int ct = 0; ct < 2; ++ct)
                    acc[rt][ct] = __builtin_amdgcn_mfma_f32_16x16x32_bf16(a, b[ct], acc[rt][ct], 0, 0, 0);
            }
        }
    }

    // phase-1 epilogue: h4 tile (bf16) into LDS, all rows (tail rows harmless)
    #pragma unroll
    for (int rt = 0; rt < 4; ++rt) {
        #pragma unroll
        for (int ct = 0; ct < 2; ++ct) {
            const int c = w * 32 + ct * 16 + r16;
            const float bv = bias1[c];
            #pragma unroll
            for (int r = 0; r < 4; ++r) {
                int lrow = rt * 16 + (lane >> 4) * 4 + r;
                sH[lrow * SHP + c] = f2b(fmaxf(acc[rt][ct][r] + bv, 0.0f));
            }
        }
    }
    __syncthreads();

    // phase 2: FC from LDS
    f32x4 acc2[4][2];
    #pragma unroll
    for (int i = 0; i < 4; ++i)
        #pragma unroll
        for (int j = 0; j < 2; ++j) acc2[i][j] = (f32x4){0.f, 0.f, 0.f, 0.f};

    #pragma unroll
    for (int kk = 0; kk < 4; ++kk) {
        const int k0 = kk * 32 + kq;
        bf16x8 b[2];
        #pragma unroll
        for (int ct = 0; ct < 2; ++ct) {
            int o = w * 32 + ct * 16 + r16;
            b[ct] = *reinterpret_cast<const bf16x8*>(Wf + o * DF + k0);
        }
        #pragma unroll
        for (int rt = 0; rt < 4; ++rt) {
            bf16x8 a = *reinterpret_cast<const bf16x8*>(&sH[(rt * 16 + r16) * SHP + k0]);
            #pragma unroll
            for (int ct = 0; ct < 2; ++ct)
                acc2[rt][ct] = __builtin_amdgcn_mfma_f32_16x16x32_bf16(a, b[ct], acc2[rt][ct], 0, 0, 0);
        }
    }

    #pragma unroll
    for (int rt = 0; rt < 4; ++rt) {
        #pragma unroll
        for (int ct = 0; ct < 2; ++ct) {
            const int c = w * 32 + ct * 16 + r16;
            const float bv = biasf[c];
            #pragma unroll
            for (int r = 0; r < 4; ++r) {
                int row = n0 + rt * 16 + (lane >> 4) * 4 + r;
                if (row < n)
                    out[(long long)row * DF + c] = acc2[rt][ct][r] + bv;
            }
        }
    }
}

extern "C" void kernel_launch(void* const* d_in, const int* in_sizes, int n_in,
                              void* d_out, int out_size, void* d_ws, size_t ws_size,
                              hipStream_t stream) {
    const float* x  = (const float*)d_in[0];
    const int*   ei = (const int*)d_in[1];   // int64 in reference -> int32 from harness
    const int N = in_sizes[0] / DF;
    const int E = in_sizes[1] / 2;
    const int* src = ei;
    const int* dst = ei + E;

    const float* b1  = (const float*)d_in[4];
    const float* b2  = (const float*)d_in[7];
    const float* b3  = (const float*)d_in[10];
    const float* b4  = (const float*)d_in[13];
    const float* bfc = (const float*)d_in[15];

    float* out = (float*)d_out;

    // workspace layout
    char* ws = (char*)d_ws;
    size_t off = 0;
    auto alloc = [&](size_t bytes) { char* p = ws + off; off = (off + bytes + 255) & ~(size_t)255; return p; };
    int*    cnt       = (int*)   alloc((size_t)N * 4);
    int*    row_start = (int*)   alloc((size_t)(N + 1) * 4);
    int*    cur       = (int*)   alloc((size_t)N * 4);
    float*  inv       = (float*) alloc((size_t)N * 4);
    int*    bsum      = (int*)   alloc(256 * 4);
    ushort* col       = (ushort*)alloc((size_t)E * 2);
    ushort* Xb        = (ushort*)alloc((size_t)N * DF * 2);
    ushort* M         = (ushort*)alloc((size_t)N * DF * 2);
    ushort* H         = (ushort*)alloc((size_t)N * DF * 2);
    ushort* Wb        = (ushort*)alloc((size_t)9 * 16384 * 2);

    // one-time prep: CSR + bf16 conversions
    hipMemsetAsync(cnt, 0, (size_t)N * 4, stream);
    count_kernel<<<dim3((E + 255) / 256), dim3(256), 0, stream>>>(dst, cnt, E);
    const int nb = (N + SCAN_TILE - 1) / SCAN_TILE;   // 25 for N=50000 (<=64 required)
    scan_reduce<<<dim3(nb), dim3(256), 0, stream>>>(cnt, bsum, N);
    scan_blocksums<<<dim3(1), dim3(64), 0, stream>>>(bsum, nb, row_start, N);
    scan_apply<<<dim3(nb), dim3(256), 0, stream>>>(cnt, bsum, row_start, cur, inv, N);
    place_kernel<<<dim3((E + 255) / 256), dim3(256), 0, stream>>>(src, dst, cur, col, E);

    const int n4 = N * DF / 4;
    cvt_x_kernel<<<dim3((n4 + 255) / 256), dim3(256), 0, stream>>>(x, Xb, n4);
    WPtrs wp;
    wp.p[0] = (const float*)d_in[2];  wp.p[1] = (const float*)d_in[3];   // W1l W1r
    wp.p[2] = (const float*)d_in[5];  wp.p[3] = (const float*)d_in[6];   // W2l W2r
    wp.p[4] = (const float*)d_in[8];  wp.p[5] = (const float*)d_in[9];   // W3l W3r
    wp.p[6] = (const float*)d_in[11]; wp.p[7] = (const float*)d_in[12];  // W4l W4r
    wp.p[8] = (const float*)d_in[14];                                    // Wfc
    cvt_w_kernel<<<dim3(64, 9), dim3(256), 0, stream>>>(wp, Wb);

    const int agrid = (N + 3) / 4;
    const int ggrid = (N + 63) / 64;

    // L1
    aggregate_kernel<<<dim3(agrid), dim3(256), 0, stream>>>(Xb, row_start, col, inv, M, N);
    gemm_mfma<<<dim3(ggrid), dim3(256), 0, stream>>>(M, Xb, Wb + 0*16384, Wb + 1*16384, b1, H, N);
    // L2
    aggregate_kernel<<<dim3(agrid), dim3(256), 0, stream>>>(H, row_start, col, inv, M, N);
    gemm_mfma<<<dim3(ggrid), dim3(256), 0, stream>>>(M, H, Wb + 2*16384, Wb + 3*16384, b2, H, N);
    // L3
    aggregate_kernel<<<dim3(agrid), dim3(256), 0, stream>>>(H, row_start, col, inv, M, N);
    gemm_mfma<<<dim3(ggrid), dim3(256), 0, stream>>>(M, H, Wb + 4*16384, Wb + 5*16384, b3, H, N);
    // L4 + FC fused
    aggregate_kernel<<<dim3(agrid), dim3(256), 0, stream>>>(H, row_start, col, inv, M, N);
    gemm_mfma_fc<<<dim3(ggrid), dim3(256), 0, stream>>>(M, H, Wb + 6*16384, Wb + 7*16384, b4,
                                                        Wb + 8*16384, bfc, out, N);
}

// Round 13
// 308.408 us; speedup vs baseline: 1.1376x; 1.1376x over previous
//
#include <hip/hip_runtime.h>

#define DF 128
#define SCAN_TILE 2048   // elements per scan block (256 thr x 8)
#define SHP 136          // LDS ushort stride: 272B rows, 2-way bank alias (free)

typedef __attribute__((ext_vector_type(8))) short bf16x8;
typedef __attribute__((ext_vector_type(4))) float f32x4;

__device__ __forceinline__ ushort f2b(float f) {      // f32 -> bf16 RNE
    uint u = __float_as_uint(f);
    u += 0x7FFF + ((u >> 16) & 1);
    return (ushort)(u >> 16);
}
__device__ __forceinline__ float blo(uint v) { return __uint_as_float(v << 16); }
__device__ __forceinline__ float bhi(uint v) { return __uint_as_float(v & 0xFFFF0000u); }
__device__ __forceinline__ uint pk(float lo, float hi) {
    return (uint)f2b(lo) | ((uint)f2b(hi) << 16);
}

// ---------- CSR build ----------

__global__ void count_kernel(const int* __restrict__ dst, int* __restrict__ cnt, int E) {
    int e = blockIdx.x * blockDim.x + threadIdx.x;
    if (e < E) atomicAdd(&cnt[dst[e]], 1);
}

__global__ __launch_bounds__(256) void scan_reduce(const int* __restrict__ cnt,
                                                   int* __restrict__ bsum, int N) {
    __shared__ int sw[4];
    const int tid = threadIdx.x, lane = tid & 63, wid = tid >> 6;
    const int base = blockIdx.x * SCAN_TILE + tid * 8;
    int s = 0;
    #pragma unroll
    for (int j = 0; j < 8; ++j) { int i = base + j; if (i < N) s += cnt[i]; }
    #pragma unroll
    for (int off = 1; off < 64; off <<= 1) s += __shfl_xor(s, off);
    if (lane == 0) sw[wid] = s;
    __syncthreads();
    if (tid == 0) bsum[blockIdx.x] = sw[0] + sw[1] + sw[2] + sw[3];
}

__global__ __launch_bounds__(64) void scan_blocksums(int* __restrict__ bsum, int nb,
                                                     int* __restrict__ row_start, int N) {
    const int lane = threadIdx.x;
    int v = (lane < nb) ? bsum[lane] : 0;
    int incl = v;
    #pragma unroll
    for (int off = 1; off < 64; off <<= 1) {
        int t = __shfl_up(incl, off);
        if (lane >= off) incl += t;
    }
    if (lane < nb) bsum[lane] = incl - v;          // exclusive
    if (lane == 63) row_start[N] = incl;           // grand total
}

__global__ __launch_bounds__(256) void scan_apply(const int* __restrict__ cnt,
                                                  const int* __restrict__ bsum,
                                                  int* __restrict__ row_start,
                                                  int* __restrict__ cur,
                                                  float* __restrict__ inv, int N) {
    __shared__ int sw[4];
    const int tid = threadIdx.x, lane = tid & 63, wid = tid >> 6;
    const int base = blockIdx.x * SCAN_TILE + tid * 8;
    int v[8];
    int tsum = 0;
    #pragma unroll
    for (int j = 0; j < 8; ++j) {
        int i = base + j;
        v[j] = (i < N) ? cnt[i] : 0;
        tsum += v[j];
    }
    int incl = tsum;
    #pragma unroll
    for (int off = 1; off < 64; off <<= 1) {
        int t = __shfl_up(incl, off);
        if (lane >= off) incl += t;
    }
    if (lane == 63) sw[wid] = incl;
    __syncthreads();
    int woff = 0;
    #pragma unroll
    for (int k = 0; k < 4; ++k) woff += (k < wid) ? sw[k] : 0;
    int run = bsum[blockIdx.x] + woff + (incl - tsum);
    #pragma unroll
    for (int j = 0; j < 8; ++j) {
        int i = base + j;
        if (i < N) {
            row_start[i] = run;
            cur[i]       = run;
            inv[i]       = 1.0f / fmaxf((float)v[j], 1.0f);
        }
        run += v[j];
    }
}

__global__ void place_kernel(const int* __restrict__ src, const int* __restrict__ dst,
                             int* __restrict__ cur, ushort* __restrict__ col, int E) {
    int e = blockIdx.x * blockDim.x + threadIdx.x;
    if (e < E) {
        int p = atomicAdd(&cur[dst[e]], 1);
        col[p] = (ushort)src[e];          // N=50000 < 65536
    }
}

// ---------- conversions ----------

__global__ void cvt_x_kernel(const float* __restrict__ in, ushort* __restrict__ out, int n4) {
    int i = blockIdx.x * blockDim.x + threadIdx.x;   // index of float4
    if (i < n4) {
        float4 v = *reinterpret_cast<const float4*>(in + (long long)i * 4);
        uint2 p;
        p.x = pk(v.x, v.y);
        p.y = pk(v.z, v.w);
        *reinterpret_cast<uint2*>(out + (long long)i * 4) = p;
    }
}

struct WPtrs { const float* p[9]; };

__global__ void cvt_w_kernel(WPtrs w, ushort* __restrict__ out) {
    int m = blockIdx.y;
    int i = blockIdx.x * 256 + threadIdx.x;          // 0..16383
    out[m * 16384 + i] = f2b(w.p[m][i]);
}

// ---------- aggregate: bf16 gather-mean, wave per node, half-wave MLP ----------

__global__ __launch_bounds__(256) void aggregate_kernel(
        const ushort* __restrict__ H,
        const int* __restrict__ row_start, const ushort* __restrict__ col,
        const float* __restrict__ inv, ushort* __restrict__ M, int N) {
    const int node = blockIdx.x * 4 + (threadIdx.x >> 6);
    const int lane = threadIdx.x & 63;
    if (node >= N) return;
    const int s = row_start[node], e = row_start[node + 1];
    const int half = lane >> 5, l32 = lane & 31;
    const uint2* __restrict__ Hu = reinterpret_cast<const uint2*>(H);
    float a0 = 0.f, a1 = 0.f, a2 = 0.f, a3 = 0.f;
    int j = s;
    for (; j + 8 <= e; j += 8) {
        int n0 = (int)col[j + 0 + half];
        int n1 = (int)col[j + 2 + half];
        int n2 = (int)col[j + 4 + half];
        int n3 = (int)col[j + 6 + half];
        uint2 v0 = Hu[n0 * 32 + l32];
        uint2 v1 = Hu[n1 * 32 + l32];
        uint2 v2 = Hu[n2 * 32 + l32];
        uint2 v3 = Hu[n3 * 32 + l32];
        a0 += blo(v0.x); a1 += bhi(v0.x); a2 += blo(v0.y); a3 += bhi(v0.y);
        a0 += blo(v1.x); a1 += bhi(v1.x); a2 += blo(v1.y); a3 += bhi(v1.y);
        a0 += blo(v2.x); a1 += bhi(v2.x); a2 += blo(v2.y); a3 += bhi(v2.y);
        a0 += blo(v3.x); a1 += bhi(v3.x); a2 += blo(v3.y); a3 += bhi(v3.y);
    }
    for (; j + 2 <= e; j += 2) {
        int n0 = (int)col[j + half];
        uint2 v0 = Hu[n0 * 32 + l32];
        a0 += blo(v0.x); a1 += bhi(v0.x); a2 += blo(v0.y); a3 += bhi(v0.y);
    }
    if (j < e && half == 0) {
        int n0 = (int)col[j];
        uint2 v0 = Hu[n0 * 32 + l32];
        a0 += blo(v0.x); a1 += bhi(v0.x); a2 += blo(v0.y); a3 += bhi(v0.y);
    }
    a0 += __shfl_xor(a0, 32);
    a1 += __shfl_xor(a1, 32);
    a2 += __shfl_xor(a2, 32);
    a3 += __shfl_xor(a3, 32);
    if (half == 0) {
        const float iv = inv[node];
        uint2 p;
        p.x = pk(a0 * iv, a1 * iv);
        p.y = pk(a2 * iv, a3 * iv);
        reinterpret_cast<uint2*>(M + (long long)node * DF)[l32] = p;
    }
}

// ---------- LDS tile staging: 64x128 bf16 -> [64][SHP] padded ----------
// 8x16B global loads in flight per thread (both tiles), one bulk wait, ds_writes.
__device__ __forceinline__ void stage2(const ushort* __restrict__ g1,
                                       const ushort* __restrict__ g2,
                                       ushort* s1, ushort* s2, int tid) {
    bf16x8 v1[4], v2[4];
    #pragma unroll
    for (int q = 0; q < 4; ++q) {
        int idx = q * 256 + tid;
        int row = idx >> 4, ch = (idx & 15) * 8;
        v1[q] = *reinterpret_cast<const bf16x8*>(g1 + row * DF + ch);
        v2[q] = *reinterpret_cast<const bf16x8*>(g2 + row * DF + ch);
    }
    #pragma unroll
    for (int q = 0; q < 4; ++q) {
        int idx = q * 256 + tid;
        int row = idx >> 4, ch = (idx & 15) * 8;
        *reinterpret_cast<bf16x8*>(s1 + row * SHP + ch) = v1[q];
        *reinterpret_cast<bf16x8*>(s2 + row * SHP + ch) = v2[q];
    }
}

// ---------- dual-GEMM via MFMA, LDS-staged A: outB = relu(A1@W1.T + A2@W2.T + b) ----------
// block = 64 rows x 128 cols, 4 waves; wave w owns cols [w*32, w*32+32).
// In-place safe: tiles staged before any write; block writes only its own rows.

__global__ __launch_bounds__(256) void gemm_mfma(
    const ushort* __restrict__ A1,
    const ushort* __restrict__ A2,
    const ushort* __restrict__ W1,
    const ushort* __restrict__ W2,
    const float* __restrict__ bias,
    ushort* __restrict__ outB,
    int n)
{
    __shared__ ushort sA1[64 * SHP];
    __shared__ ushort sA2[64 * SHP];

    const int tid  = threadIdx.x;
    const int lane = tid & 63;
    const int w    = tid >> 6;
    const int n0   = blockIdx.x * 64;
    const int r16  = lane & 15;
    const int kq   = (lane >> 4) * 8;

    stage2(A1 + (long long)n0 * DF, A2 + (long long)n0 * DF, sA1, sA2, tid);
    __syncthreads();

    f32x4 acc[4][2];
    #pragma unroll
    for (int i = 0; i < 4; ++i)
        #pragma unroll
        for (int j = 0; j < 2; ++j) acc[i][j] = (f32x4){0.f, 0.f, 0.f, 0.f};

    #pragma unroll
    for (int pass = 0; pass < 2; ++pass) {
        const ushort* sA = pass ? sA2 : sA1;
        const ushort* W  = pass ? W2 : W1;
        #pragma unroll
        for (int kk = 0; kk < 4; ++kk) {
            const int k0 = kk * 32 + kq;
            bf16x8 b[2];
            #pragma unroll
            for (int ct = 0; ct < 2; ++ct) {
                int o = w * 32 + ct * 16 + r16;
                b[ct] = *reinterpret_cast<const bf16x8*>(W + o * DF + k0);
            }
            #pragma unroll
            for (int rt = 0; rt < 4; ++rt) {
                bf16x8 a = *reinterpret_cast<const bf16x8*>(sA + (rt * 16 + r16) * SHP + k0);
                #pragma unroll
                for (int ct = 0; ct < 2; ++ct)
                    acc[rt][ct] = __builtin_amdgcn_mfma_f32_16x16x32_bf16(a, b[ct], acc[rt][ct], 0, 0, 0);
            }
        }
    }

    // C/D layout: col = lane&15, row = (lane>>4)*4 + reg
    #pragma unroll
    for (int rt = 0; rt < 4; ++rt) {
        #pragma unroll
        for (int ct = 0; ct < 2; ++ct) {
            const int c = w * 32 + ct * 16 + r16;
            const float bv = bias[c];
            #pragma unroll
            for (int r = 0; r < 4; ++r) {
                int row = n0 + rt * 16 + (lane >> 4) * 4 + r;
                if (row < n) {
                    float v = fmaxf(acc[rt][ct][r] + bv, 0.0f);
                    outB[(long long)row * DF + c] = f2b(v);
                }
            }
        }
    }
}

// ---------- fused L4 + FC (LDS-staged): h4 = relu(..) -> reuse sA1; out = h4@Wf.T + bf ----------

__global__ __launch_bounds__(256) void gemm_mfma_fc(
    const ushort* __restrict__ A1,
    const ushort* __restrict__ A2,
    const ushort* __restrict__ W1,
    const ushort* __restrict__ W2,
    const float* __restrict__ bias1,
    const ushort* __restrict__ Wf,
    const float* __restrict__ biasf,
    float* __restrict__ out,
    int n)
{
    __shared__ ushort sA1[64 * SHP];   // M tile, later reused as h4 tile
    __shared__ ushort sA2[64 * SHP];

    const int tid  = threadIdx.x;
    const int lane = tid & 63;
    const int w    = tid >> 6;
    const int n0   = blockIdx.x * 64;
    const int r16  = lane & 15;
    const int kq   = (lane >> 4) * 8;

    stage2(A1 + (long long)n0 * DF, A2 + (long long)n0 * DF, sA1, sA2, tid);
    __syncthreads();

    f32x4 acc[4][2];
    #pragma unroll
    for (int i = 0; i < 4; ++i)
        #pragma unroll
        for (int j = 0; j < 2; ++j) acc[i][j] = (f32x4){0.f, 0.f, 0.f, 0.f};

    #pragma unroll
    for (int pass = 0; pass < 2; ++pass) {
        const ushort* sA = pass ? sA2 : sA1;
        const ushort* W  = pass ? W2 : W1;
        #pragma unroll
        for (int kk = 0; kk < 4; ++kk) {
            const int k0 = kk * 32 + kq;
            bf16x8 b[2];
            #pragma unroll
            for (int ct = 0; ct < 2; ++ct) {
                int o = w * 32 + ct * 16 + r16;
                b[ct] = *reinterpret_cast<const bf16x8*>(W + o * DF + k0);
            }
            #pragma unroll
            for (int rt = 0; rt < 4; ++rt) {
                bf16x8 a = *reinterpret_cast<const bf16x8*>(sA + (rt * 16 + r16) * SHP + k0);
                #pragma unroll
                for (int ct = 0; ct < 2; ++ct)
                    acc[rt][ct] = __builtin_amdgcn_mfma_f32_16x16x32_bf16(a, b[ct], acc[rt][ct], 0, 0, 0);
            }
        }
    }

    __syncthreads();   // all waves done reading sA1 before overwrite with h4

    #pragma unroll
    for (int rt = 0; rt < 4; ++rt) {
        #pragma unroll
        for (int ct = 0; ct < 2; ++ct) {
            const int c = w * 32 + ct * 16 + r16;
            const float bv = bias1[c];
            #pragma unroll
            for (int r = 0; r < 4; ++r) {
                int lrow = rt * 16 + (lane >> 4) * 4 + r;
                sA1[lrow * SHP + c] = f2b(fmaxf(acc[rt][ct][r] + bv, 0.0f));
            }
        }
    }
    __syncthreads();

    // phase 2: FC from LDS (h4 in sA1)
    f32x4 acc2[4][2];
    #pragma unroll
    for (int i = 0; i < 4; ++i)
        #pragma unroll
        for (int j = 0; j < 2; ++j) acc2[i][j] = (f32x4){0.f, 0.f, 0.f, 0.f};

    #pragma unroll
    for (int kk = 0; kk < 4; ++kk) {
        const int k0 = kk * 32 + kq;
        bf16x8 b[2];
        #pragma unroll
        for (int ct = 0; ct < 2; ++ct) {
            int o = w * 32 + ct * 16 + r16;
            b[ct] = *reinterpret_cast<const bf16x8*>(Wf + o * DF + k0);
        }
        #pragma unroll
        for (int rt = 0; rt < 4; ++rt) {
            bf16x8 a = *reinterpret_cast<const bf16x8*>(&sA1[(rt * 16 + r16) * SHP + k0]);
            #pragma unroll
            for (int ct = 0; ct < 2; ++ct)
                acc2[rt][ct] = __builtin_amdgcn_mfma_f32_16x16x32_bf16(a, b[ct], acc2[rt][ct], 0, 0, 0);
        }
    }

    #pragma unroll
    for (int rt = 0; rt < 4; ++rt) {
        #pragma unroll
        for (int ct = 0; ct < 2; ++ct) {
            const int c = w * 32 + ct * 16 + r16;
            const float bv = biasf[c];
            #pragma unroll
            for (int r = 0; r < 4; ++r) {
                int row = n0 + rt * 16 + (lane >> 4) * 4 + r;
                if (row < n)
                    out[(long long)row * DF + c] = acc2[rt][ct][r] + bv;
            }
        }
    }
}

extern "C" void kernel_launch(void* const* d_in, const int* in_sizes, int n_in,
                              void* d_out, int out_size, void* d_ws, size_t ws_size,
                              hipStream_t stream) {
    const float* x  = (const float*)d_in[0];
    const int*   ei = (const int*)d_in[1];   // int64 in reference -> int32 from harness
    const int N = in_sizes[0] / DF;
    const int E = in_sizes[1] / 2;
    const int* src = ei;
    const int* dst = ei + E;

    const float* b1  = (const float*)d_in[4];
    const float* b2  = (const float*)d_in[7];
    const float* b3  = (const float*)d_in[10];
    const float* b4  = (const float*)d_in[13];
    const float* bfc = (const float*)d_in[15];

    float* out = (float*)d_out;

    // workspace layout
    char* ws = (char*)d_ws;
    size_t off = 0;
    auto alloc = [&](size_t bytes) { char* p = ws + off; off = (off + bytes + 255) & ~(size_t)255; return p; };
    int*    cnt       = (int*)   alloc((size_t)N * 4);
    int*    row_start = (int*)   alloc((size_t)(N + 1) * 4);
    int*    cur       = (int*)   alloc((size_t)N * 4);
    float*  inv       = (float*) alloc((size_t)N * 4);
    int*    bsum      = (int*)   alloc(256 * 4);
    ushort* col       = (ushort*)alloc((size_t)E * 2);
    ushort* Xb        = (ushort*)alloc((size_t)N * DF * 2);
    ushort* M         = (ushort*)alloc((size_t)N * DF * 2);
    ushort* H         = (ushort*)alloc((size_t)N * DF * 2);
    ushort* Wb        = (ushort*)alloc((size_t)9 * 16384 * 2);
    (void)alloc(16384);   // slack so tail-block staging over-reads stay in ws

    // one-time prep: CSR + bf16 conversions
    hipMemsetAsync(cnt, 0, (size_t)N * 4, stream);
    count_kernel<<<dim3((E + 255) / 256), dim3(256), 0, stream>>>(dst, cnt, E);
    const int nb = (N + SCAN_TILE - 1) / SCAN_TILE;   // 25 for N=50000 (<=64 required)
    scan_reduce<<<dim3(nb), dim3(256), 0, stream>>>(cnt, bsum, N);
    scan_blocksums<<<dim3(1), dim3(64), 0, stream>>>(bsum, nb, row_start, N);
    scan_apply<<<dim3(nb), dim3(256), 0, stream>>>(cnt, bsum, row_start, cur, inv, N);
    place_kernel<<<dim3((E + 255) / 256), dim3(256), 0, stream>>>(src, dst, cur, col, E);

    const int n4 = N * DF / 4;
    cvt_x_kernel<<<dim3((n4 + 255) / 256), dim3(256), 0, stream>>>(x, Xb, n4);
    WPtrs wp;
    wp.p[0] = (const float*)d_in[2];  wp.p[1] = (const float*)d_in[3];   // W1l W1r
    wp.p[2] = (const float*)d_in[5];  wp.p[3] = (const float*)d_in[6];   // W2l W2r
    wp.p[4] = (const float*)d_in[8];  wp.p[5] = (const float*)d_in[9];   // W3l W3r
    wp.p[6] = (const float*)d_in[11]; wp.p[7] = (const float*)d_in[12];  // W4l W4r
    wp.p[8] = (const float*)d_in[14];                                    // Wfc
    cvt_w_kernel<<<dim3(64, 9), dim3(256), 0, stream>>>(wp, Wb);

    const int agrid = (N + 3) / 4;
    const int ggrid = (N + 63) / 64;

    // L1
    aggregate_kernel<<<dim3(agrid), dim3(256), 0, stream>>>(Xb, row_start, col, inv, M, N);
    gemm_mfma<<<dim3(ggrid), dim3(256), 0, stream>>>(M, Xb, Wb + 0*16384, Wb + 1*16384, b1, H, N);
    // L2
    aggregate_kernel<<<dim3(agrid), dim3(256), 0, stream>>>(H, row_start, col, inv, M, N);
    gemm_mfma<<<dim3(ggrid), dim3(256), 0, stream>>>(M, H, Wb + 2*16384, Wb + 3*16384, b2, H, N);
    // L3
    aggregate_kernel<<<dim3(agrid), dim3(256), 0, stream>>>(H, row_start, col, inv, M, N);
    gemm_mfma<<<dim3(ggrid), dim3(256), 0, stream>>>(M, H, Wb + 4*16384, Wb + 5*16384, b3, H, N);
    // L4 + FC fused
    aggregate_kernel<<<dim3(agrid), dim3(256), 0, stream>>>(H, row_start, col, inv, M, N);
    gemm_mfma_fc<<<dim3(ggrid), dim3(256), 0, stream>>>(M, H, Wb + 6*16384, Wb + 7*16384, b4,
                                                        Wb + 8*16384, bfc, out, N);
}